// Round 1
// baseline (85.464 us; speedup 1.0000x reference)
//
#include <hip/hip_runtime.h>
#include <math.h>

#define NW 4
#define NL 3

struct cplx { float re, im; };
__device__ __forceinline__ cplx cmul(cplx a, cplx b){ return {a.re*b.re - a.im*b.im, a.re*b.im + a.im*b.re}; }
__device__ __forceinline__ cplx cadd(cplx a, cplx b){ return {a.re+b.re, a.im+b.im}; }

// ---------------------------------------------------------------------------
// Kernel 1 (one block, 256 threads): build the fixed 16x16 circuit unitary U
// from ansatz_params, form C_j = sum_w W[j][w] * Re(U^dag D_w U), then
// Pauli-contract to the 81x4 multilinear coefficient tensor T. Bias folded
// into T[k=0]. Writes 324 floats to ws.
// ---------------------------------------------------------------------------
__global__ void precompute_T(const float* __restrict__ params,  // (3,4,3)
                             const float* __restrict__ W,       // (4,4)
                             const float* __restrict__ bias,    // (4,)
                             float* __restrict__ ws)
{
    __shared__ float Ure[16][16], Uim[16][16];
    __shared__ float C[4][16][16];
    const int tid = threadIdx.x;
    const int s = tid >> 4, c = tid & 15;   // bit_w(s) = (s >> (3-w)) & 1

    Ure[s][c] = (s == c) ? 1.f : 0.f;
    Uim[s][c] = 0.f;
    __syncthreads();

    for (int l = 0; l < NL; ++l) {
        // Rot(phi,theta,omega) = RZ(om) RY(th) RZ(phi) on each wire
        for (int w = 0; w < NW; ++w) {
            float phi = params[(l*NW + w)*3 + 0];
            float th  = params[(l*NW + w)*3 + 1];
            float om  = params[(l*NW + w)*3 + 2];
            float st, ct; sincosf(0.5f*th, &st, &ct);
            float sp, cp; sincosf(-0.5f*(phi+om), &sp, &cp); // e^{-i(phi+om)/2} = cp + i*sp
            float sm, cm; sincosf(-0.5f*(phi-om), &sm, &cm); // e^{-i(phi-om)/2} = cm + i*sm
            cplx m00 = {  cp*ct,  sp*ct };
            cplx m01 = { -cm*st,  sm*st };   // -conj(e^{-i(phi-om)/2}) * st
            cplx m10 = {  cm*st,  sm*st };
            cplx m11 = {  cp*ct, -sp*ct };   //  conj(e^{-i(phi+om)/2}) * ct
            int mask = 1 << (3 - w);
            int b = (s & mask) ? 1 : 0;
            int s0 = s & ~mask, s1 = s | mask;
            cplx g0 = b ? m10 : m00;
            cplx g1 = b ? m11 : m01;
            cplx u0 = { Ure[s0][c], Uim[s0][c] };
            cplx u1 = { Ure[s1][c], Uim[s1][c] };
            cplx nv = cadd(cmul(g0,u0), cmul(g1,u1));
            __syncthreads();
            Ure[s][c] = nv.re; Uim[s][c] = nv.im;
            __syncthreads();
        }
        // CNOT ring with range r
        int r = (l % (NW-1)) + 1;
        for (int w = 0; w < NW; ++w) {
            int ctrl = w, tgt = (w + r) % NW;
            int cmk = 1 << (3 - ctrl), tmk = 1 << (3 - tgt);
            int src = (s & cmk) ? (s ^ tmk) : s;
            float vr = Ure[src][c], vi = Uim[src][c];
            __syncthreads();
            Ure[s][c] = vr; Uim[s][c] = vi;
            __syncthreads();
        }
    }

    // C_j[s][t] = sum_w W[j][w] * Re( sum_r conj(U[r][s]) z_w(r) U[r][t] )
    {
        float A[4];
        for (int w = 0; w < NW; ++w) {
            int mask = 1 << (3 - w);
            float acc = 0.f;
            for (int rr = 0; rr < 16; ++rr) {
                float zs = (rr & mask) ? -1.f : 1.f;
                acc += zs * (Ure[rr][s]*Ure[rr][c] + Uim[rr][s]*Uim[rr][c]);
            }
            A[w] = acc;
        }
        for (int j = 0; j < 4; ++j) {
            float cj = 0.f;
            for (int w = 0; w < NW; ++w) cj += W[j*4 + w] * A[w];
            C[j][s][c] = cj;
        }
    }
    __syncthreads();

    // T[k][j] = (1/16) sum_{s,t} C_j[s,t] * prod_w sigma_{k_w}[s_w,t_w]
    // sigma_0=I, sigma_1=Z, sigma_2=X; only 16 nonzero (s,t) pairs per k.
    if (tid < 81) {
        int k = tid;
        int kw[4] = { k/27, (k/9)%3, (k/3)%3, k%3 };
        int sb[4][2], tb[4][2]; float sg[4][2];
        for (int w = 0; w < 4; ++w) {
            int kk = kw[w];
            if (kk == 0)      { sb[w][0]=0; tb[w][0]=0; sg[w][0]= 1.f; sb[w][1]=1; tb[w][1]=1; sg[w][1]= 1.f; }
            else if (kk == 1) { sb[w][0]=0; tb[w][0]=0; sg[w][0]= 1.f; sb[w][1]=1; tb[w][1]=1; sg[w][1]=-1.f; }
            else              { sb[w][0]=0; tb[w][0]=1; sg[w][0]= 1.f; sb[w][1]=1; tb[w][1]=0; sg[w][1]= 1.f; }
        }
        float acc[4] = {0.f,0.f,0.f,0.f};
        for (int m = 0; m < 16; ++m) {
            int ss = 0, tt = 0; float sign = 1.f;
            for (int w = 0; w < 4; ++w) {
                int o = (m >> (3-w)) & 1;
                ss |= sb[w][o] << (3-w);
                tt |= tb[w][o] << (3-w);
                sign *= sg[w][o];
            }
            for (int j = 0; j < 4; ++j) acc[j] += sign * C[j][ss][tt];
        }
        for (int j = 0; j < 4; ++j) {
            float v = acc[j] * (1.f/16.f);
            if (k == 0) v += bias[j];     // fold bias into the constant term
            ws[k*4 + j] = v;
        }
    }
}

// ---------------------------------------------------------------------------
// Kernel 2: one thread = 2 horizontally adjacent patches.
// out_j(a) = sum_{u,v} T[u*9+v][j] * p01[u] * p23[v]
// where p01 = (1,cos a0,sin a0) x (1,cos a1,sin a1), p23 likewise.
// ---------------------------------------------------------------------------
__device__ __forceinline__ void build9(float a0, float a1, float* p) {
    float c0, s0, c1, s1;
    __sincosf(a0, &s0, &c0);
    __sincosf(a1, &s1, &c1);
    p[0] = 1.f;  p[1] = c1;    p[2] = s1;
    p[3] = c0;   p[4] = c0*c1; p[5] = c0*s1;
    p[6] = s0;   p[7] = s0*c1; p[8] = s0*s1;
}

__global__ __launch_bounds__(256) void quanv_main(const float* __restrict__ x,
                                                  const float* __restrict__ T,
                                                  float* __restrict__ out)
{
    __shared__ float4 sT[81];
    const int tid = threadIdx.x;
    if (tid < 81) sT[tid] = ((const float4*)T)[tid];
    __syncthreads();

    int t   = blockIdx.x * 256 + tid;      // 4096*14*7 = 401408 threads exact
    int jt  = t % 7;
    int rem = t / 7;
    int i   = rem % 14;
    int b   = rem / 14;

    const float* base = x + b*784 + (2*i)*28 + 4*jt;
    float4 r0 = *(const float4*)(base);        // row 2i,   cols 4jt..4jt+3
    float4 r1 = *(const float4*)(base + 28);   // row 2i+1, cols 4jt..4jt+3

    float pA01[9], pA23[9], pB01[9], pB23[9];
    build9(r0.x, r0.y, pA01);  build9(r1.x, r1.y, pA23);   // patch A (j=2jt)
    build9(r0.z, r0.w, pB01);  build9(r1.z, r1.w, pB23);   // patch B (j=2jt+1)

    float oA0=0.f,oA1=0.f,oA2=0.f,oA3=0.f;
    float oB0=0.f,oB1=0.f,oB2=0.f,oB3=0.f;
    #pragma unroll
    for (int u = 0; u < 9; ++u) {
        float au = pA01[u], bu = pB01[u];
        #pragma unroll
        for (int v = 0; v < 9; ++v) {
            float4 tv = sT[u*9 + v];           // wave-uniform LDS broadcast
            float qA = au * pA23[v];
            float qB = bu * pB23[v];
            oA0 = fmaf(tv.x, qA, oA0);  oB0 = fmaf(tv.x, qB, oB0);
            oA1 = fmaf(tv.y, qA, oA1);  oB1 = fmaf(tv.y, qB, oB1);
            oA2 = fmaf(tv.z, qA, oA2);  oB2 = fmaf(tv.z, qB, oB2);
            oA3 = fmaf(tv.w, qA, oA3);  oB3 = fmaf(tv.w, qB, oB3);
        }
    }

    int p = b*196 + i*14 + 2*jt;               // flat patch index
    float4* o = (float4*)out + p;
    o[0] = make_float4(oA0, oA1, oA2, oA3);
    o[1] = make_float4(oB0, oB1, oB2, oB3);
}

extern "C" void kernel_launch(void* const* d_in, const int* in_sizes, int n_in,
                              void* d_out, int out_size, void* d_ws, size_t ws_size,
                              hipStream_t stream) {
    const float* x      = (const float*)d_in[0];   // (4096,1,28,28)
    const float* params = (const float*)d_in[1];   // (3,4,3)
    const float* W      = (const float*)d_in[2];   // (4,4)
    const float* bias   = (const float*)d_in[3];   // (4,)
    float* out = (float*)d_out;                    // (4096, 784)
    float* ws  = (float*)d_ws;                     // 324 floats used

    precompute_T<<<1, 256, 0, stream>>>(params, W, bias, ws);

    const int total  = 4096 * 14 * 7;              // 2 patches per thread
    const int blocks = total / 256;                // 1568
    quanv_main<<<blocks, 256, 0, stream>>>(x, ws, out);
}